// Round 5
// baseline (141.917 us; speedup 1.0000x reference)
//
#include <hip/hip_runtime.h>
#include <hip/hip_bf16.h>
#include <cstdint>
#include <cstddef>

// Problem constants (fixed by reference)
#define NE 8      // experts
#define MEt 1024  // tokens per expert
#define KD 2048   // in features
#define ND 2048   // out features
#define NG 16     // K / G  (G = 128)

// Tile config
#define BM 256
#define BN 256
#define BK 128            // one scale-group per K-step
#define NKT (KD / BK)     // 16 K-steps
#define TILE_B (BM * BK)  // 32768 bytes per packed tile (A and B same)

typedef int   i32x4  __attribute__((ext_vector_type(4)));
typedef int   i32x16 __attribute__((ext_vector_type(16)));
typedef float f32x16 __attribute__((ext_vector_type(16)));

#define A_CHUNKS ((NE * MEt * KD) / 16)   // 1048576
#define W_CHUNKS ((NE * ND * KD) / 16)    // 2097152

__device__ __forceinline__ unsigned pack4(int x0, int x1, int x2, int x3) {
    return (unsigned)(x0 & 0xFF) | ((unsigned)(x1 & 0xFF) << 8) |
           ((unsigned)(x2 & 0xFF) << 16) | ((unsigned)x3 << 24);
}

__device__ __forceinline__ void gl_lds16(const void* g, void* l) {
    // async global->LDS. LDS dest: uniform base + lane*16 (HW).
    // Global src: PER-LANE address (must include lane term!).
    __builtin_amdgcn_global_load_lds(
        (const __attribute__((address_space(1))) void*)g,
        (__attribute__((address_space(3))) void*)l, 16, 0, 0);
}

// ---------------- prepack v2: int32 -> int8, tile-contiguous K-major layout ----------------
// Packed layout: tile(panel p of 256 rows, K-step kt) is a contiguous 32KB block:
//   addr = (p*NKT + kt)*TILE_B + kchunk*(256*16) + row*16 + (k&15)
// where kchunk = (k within K-step)/16 (0..7). A: 32 panels; W: 64 panels.
__global__ __launch_bounds__(256)
void w4a8_prepack(const int* __restrict__ a_q, const int* __restrict__ w_q,
                  unsigned char* __restrict__ a8, unsigned char* __restrict__ w8)
{
    int c = blockIdx.x * 256 + threadIdx.x;   // output 16B-chunk id (linear in dst)
    const int* src;
    unsigned char* dst;
    int cc;
    if (c < A_CHUNKS)                 { src = a_q; dst = a8; cc = c; }
    else if (c < A_CHUNKS + W_CHUNKS) { src = w_q; dst = w8; cc = c - A_CHUNKS; }
    else return;

    int tile   = cc >> 11;        // 2048 chunks per 32KB tile
    int within = cc & 2047;
    int kc     = within >> 8;     // 0..7
    int r      = within & 255;    // 0..255
    int p      = tile >> 4;       // panel (256 rows)
    int kt     = tile & 15;

    // source: row (p*256 + r), elements kt*128 + kc*16 .. +15  (contiguous 64B)
    const int* gp = src + ((size_t)(p * 256 + r) * KD + kt * BK + kc * 16);
    i32x4 v0 = *(const i32x4*)(gp);
    i32x4 v1 = *(const i32x4*)(gp + 4);
    i32x4 v2 = *(const i32x4*)(gp + 8);
    i32x4 v3 = *(const i32x4*)(gp + 12);
    i32x4 pk;
    pk[0] = (int)pack4(v0[0], v0[1], v0[2], v0[3]);
    pk[1] = (int)pack4(v1[0], v1[1], v1[2], v1[3]);
    pk[2] = (int)pack4(v2[0], v2[1], v2[2], v2[3]);
    pk[3] = (int)pack4(v3[0], v3[1], v3[2], v3[3]);
    *(i32x4*)(dst + (size_t)cc * 16) = pk;    // dst linear in chunk id
}

// ---------------- main GEMM: 256x256 tile, 8 waves, glds staging, conflict-free LDS ----------------
// Stage one 32KB tile: 32 chunks of 1KB; wave wv issues 4 glds (chunks wv*4+i).
// Global src per lane: gtile + chunk*1024 + lane*16  (matches HW LDS placement base+lane*16).
__device__ __forceinline__ void stage_tile(unsigned char* lds, const unsigned char* gtile,
                                           int wv, int lane) {
#pragma unroll
    for (int i = 0; i < 4; ++i) {
        int chunk = wv * 4 + i;
        gl_lds16(gtile + chunk * 1024 + lane * 16, lds + chunk * 1024);
    }
}

__global__ __launch_bounds__(512, 2)
void w4a8_gemm_pp(const unsigned char* __restrict__ a8,   // packed, tile-contiguous
                  const unsigned char* __restrict__ w8,
                  const float* __restrict__ per_tok,      // [M]
                  const float* __restrict__ per_chan,     // [E, N]
                  const float* __restrict__ wgs,          // [E, N, NG]
                  float* __restrict__ out)                // [M, N] fp32
{
    __shared__ __align__(16) unsigned char As[2][TILE_B];
    __shared__ __align__(16) unsigned char Bs[2][TILE_B];
    __shared__ float scs[NG][BN];

    // 256 blocks: XCD-chunked -> expert e on XCD e; 32 blocks per expert per XCD
    int bid = blockIdx.x;
    int b2  = (bid & 7) * 32 + (bid >> 3);
    const int e  = b2 >> 5;        // 0..7
    const int tm = (b2 >> 3) & 3;  // 0..3 (256-row panels)
    const int tn = b2 & 7;         // 0..7 (256-col panels)

    const int tid  = threadIdx.x;
    const int lane = tid & 63;
    const int wv   = tid >> 6;   // 0..7
    const int wm   = wv >> 2;    // 0..1  (row half: 128 rows)
    const int wn   = wv & 3;     // 0..3  (col quarter: 64 cols)
    const int lcol = lane & 31;
    const int lhi  = lane >> 5;

    // panel indices in packed layout
    const unsigned char* Ag = a8 + (size_t)((e * 4 + tm) * NKT) * TILE_B;
    const unsigned char* Wg = w8 + (size_t)((e * 8 + tn) * NKT) * TILE_B;

    f32x16 facc[4][2] = {};
    const i32x16 z16 = {};

    // prologue: stage tile 0 + all group scales
    stage_tile(As[0], Ag, wv, lane);
    stage_tile(Bs[0], Wg, wv, lane);
#pragma unroll
    for (int i = 0; i < 8; ++i) {
        int idx = tid + i * 512;
        int g = idx >> 8, n = idx & 255;
        scs[g][n] = wgs[((size_t)e * ND + tn * BN + n) * NG + g];
    }
    __syncthreads();

    int c = 0;
    for (int kt = 0; kt < NKT; ++kt) {
        if (kt + 1 < NKT) {
            stage_tile(As[c ^ 1], Ag + (kt + 1) * TILE_B, wv, lane);
            stage_tile(Bs[c ^ 1], Wg + (kt + 1) * TILE_B, wv, lane);
        }
        const unsigned char* Ac = As[c];
        const unsigned char* Bc = Bs[c];

        float sc0 = scs[kt][wn * 64 +  0 + lcol];
        float sc1 = scs[kt][wn * 64 + 32 + lcol];

        // B fragments for this wave's 64 columns: [ni][ks], lane-consecutive 16B reads
        i32x4 bfr[2][4];
#pragma unroll
        for (int ni = 0; ni < 2; ++ni)
#pragma unroll
            for (int ks = 0; ks < 4; ++ks) {
                int kch = ks * 2 + lhi;
                bfr[ni][ks] = *(const i32x4*)&Bc[kch * (256 * 16) + (wn * 64 + ni * 32 + lcol) * 16];
            }

#pragma unroll
        for (int mi = 0; mi < 4; ++mi) {
            i32x4 afr[4];
#pragma unroll
            for (int ks = 0; ks < 4; ++ks) {
                int kch = ks * 2 + lhi;
                afr[ks] = *(const i32x4*)&Ac[kch * (256 * 16) + (wm * 128 + mi * 32 + lcol) * 16];
            }
            i32x16 acc0, acc1;
            acc0 = __builtin_amdgcn_mfma_i32_32x32x32_i8(afr[0], bfr[0][0], z16, 0, 0, 0);
            acc1 = __builtin_amdgcn_mfma_i32_32x32x32_i8(afr[0], bfr[1][0], z16, 0, 0, 0);
            acc0 = __builtin_amdgcn_mfma_i32_32x32x32_i8(afr[1], bfr[0][1], acc0, 0, 0, 0);
            acc1 = __builtin_amdgcn_mfma_i32_32x32x32_i8(afr[1], bfr[1][1], acc1, 0, 0, 0);
            acc0 = __builtin_amdgcn_mfma_i32_32x32x32_i8(afr[2], bfr[0][2], acc0, 0, 0, 0);
            acc1 = __builtin_amdgcn_mfma_i32_32x32x32_i8(afr[2], bfr[1][2], acc1, 0, 0, 0);
            acc0 = __builtin_amdgcn_mfma_i32_32x32x32_i8(afr[3], bfr[0][3], acc0, 0, 0, 0);
            acc1 = __builtin_amdgcn_mfma_i32_32x32x32_i8(afr[3], bfr[1][3], acc1, 0, 0, 0);
#pragma unroll
            for (int i = 0; i < 16; ++i) {
                facc[mi][0][i] += (float)acc0[i] * sc0;
                facc[mi][1][i] += (float)acc1[i] * sc1;
            }
        }
        __syncthreads();
        c ^= 1;
    }

    // epilogue: per-token and per-channel scales, store fp32
    const float* ptok  = per_tok  + e * MEt + tm * BM;
    const float* pchan = per_chan + (size_t)e * ND + tn * BN;
    float* og = out + (size_t)(e * MEt + tm * BM) * ND + tn * BN;

#pragma unroll
    for (int mi = 0; mi < 4; ++mi) {
        int mb = wm * 128 + mi * 32;
#pragma unroll
        for (int ni = 0; ni < 2; ++ni) {
            int nn = wn * 64 + ni * 32 + lcol;
            float pc = pchan[nn];
#pragma unroll
            for (int rg = 0; rg < 16; ++rg) {
                int mr = mb + (rg & 3) + 8 * (rg >> 2) + 4 * lhi;
                float pt = ptok[mr];
                og[(size_t)mr * ND + nn] = facc[mi][ni][rg] * pt * pc;
            }
        }
    }
}

extern "C" void kernel_launch(void* const* d_in, const int* in_sizes, int n_in,
                              void* d_out, int out_size, void* d_ws, size_t ws_size,
                              hipStream_t stream) {
    const int*   a_q = (const int*)d_in[0];
    const int*   w_q = (const int*)d_in[1];
    const float* pt  = (const float*)d_in[2];
    const float* pc  = (const float*)d_in[3];
    const float* wg  = (const float*)d_in[4];
    float* out = (float*)d_out;

    unsigned char* a8 = (unsigned char*)d_ws;
    unsigned char* w8 = a8 + (size_t)A_CHUNKS * 16;

    const int total_chunks = A_CHUNKS + W_CHUNKS;   // 3145728
    w4a8_prepack<<<dim3(total_chunks / 256), dim3(256), 0, stream>>>(a_q, w_q, a8, w8);
    // 8 experts * 4 m-tiles * 8 n-tiles = 256 blocks, 512 threads (8 waves)
    w4a8_gemm_pp<<<dim3(256), dim3(512), 0, stream>>>(a8, w8, pt, pc, wg, out);
}

// Round 6
// 104.629 us; speedup vs baseline: 1.3564x; 1.3564x over previous
//
#include <hip/hip_runtime.h>
#include <hip/hip_bf16.h>
#include <cstdint>
#include <cstddef>

// Problem constants (fixed by reference)
#define NE 8      // experts
#define MEt 1024  // tokens per expert
#define KD 2048   // in features
#define ND 2048   // out features
#define NG 16     // K / G  (G = 128)

// Tile config
#define BM 256
#define BN 256
#define BK 128            // one scale-group per K-step
#define NKT (KD / BK)     // 16 K-steps
#define TILE_B (BM * BK)  // 32768 bytes per packed tile (A and B same)

typedef int   i32x4  __attribute__((ext_vector_type(4)));
typedef int   i32x16 __attribute__((ext_vector_type(16)));
typedef float f32x16 __attribute__((ext_vector_type(16)));

#define A_ROWS (NE * MEt)   // 8192
#define W_ROWS (NE * ND)    // 16384
#define A_BYTES ((size_t)A_ROWS * KD)   // 16 MiB packed
#define PP_ROWS 8           // rows per prepack block

__device__ __forceinline__ unsigned pack4(int x0, int x1, int x2, int x3) {
    return (unsigned)(x0 & 0xFF) | ((unsigned)(x1 & 0xFF) << 8) |
           ((unsigned)(x2 & 0xFF) << 16) | ((unsigned)x3 << 24);
}

__device__ __forceinline__ void gl_lds16(const void* g, void* l) {
    // async global->LDS. LDS dest: uniform base + lane*16 (HW).
    // Global src: PER-LANE address (must include lane term!).
    __builtin_amdgcn_global_load_lds(
        (const __attribute__((address_space(1))) void*)g,
        (__attribute__((address_space(3))) void*)l, 16, 0, 0);
}

// ---------------- prepack v3: LDS-transposing, both sides coalesced ----------------
// Packed layout (same as v2): tile(panel p, kt) contiguous 32KB:
//   addr = (p*NKT + kt)*TILE_B + kc*(256*16) + row_in_panel*16 + (k&15)
// Block packs 8 full source rows: coalesced 16KB reads -> LDS -> 128B-segment writes.
__global__ __launch_bounds__(256)
void w4a8_prepack(const int* __restrict__ a_q, const int* __restrict__ w_q,
                  unsigned char* __restrict__ a8, unsigned char* __restrict__ w8)
{
    __shared__ __align__(16) unsigned char lbuf[PP_ROWS * KD];  // 16 KB packed rows

    const int b = blockIdx.x;
    const int tid = threadIdx.x;
    const int* src;
    unsigned char* dst;
    int rowbase;
    if (b < A_ROWS / PP_ROWS) { src = a_q; dst = a8; rowbase = b * PP_ROWS; }
    else                      { src = w_q; dst = w8; rowbase = (b - A_ROWS / PP_ROWS) * PP_ROWS; }

    // phase 1: coalesced read of 8 rows (4 x 16KB contiguous), pack, LDS stride-1 write
#pragma unroll
    for (int i = 0; i < 4; ++i) {
        int chunk = i * 256 + tid;    // 0..1023 : 64B source chunks (16 int32)
        int row   = chunk >> 7;       // 0..7
        int c64   = chunk & 127;      // 16-elem unit within row
        const int* gp = src + (size_t)(rowbase + row) * KD + c64 * 16;
        i32x4 v0 = *(const i32x4*)(gp);
        i32x4 v1 = *(const i32x4*)(gp + 4);
        i32x4 v2 = *(const i32x4*)(gp + 8);
        i32x4 v3 = *(const i32x4*)(gp + 12);
        i32x4 pk;
        pk[0] = (int)pack4(v0[0], v0[1], v0[2], v0[3]);
        pk[1] = (int)pack4(v1[0], v1[1], v1[2], v1[3]);
        pk[2] = (int)pack4(v2[0], v2[1], v2[2], v2[3]);
        pk[3] = (int)pack4(v3[0], v3[1], v3[2], v3[3]);
        *(i32x4*)&lbuf[row * KD + c64 * 16] = pk;
    }
    __syncthreads();

    // phase 2: wave wv writes kt = j*4+wv; lane -> (kc, rr); dst segments 8x128B @4KB stride
    const int wv   = tid >> 6;
    const int lane = tid & 63;
    const int kc   = lane >> 3;   // 0..7
    const int rr   = lane & 7;    // 0..7
    const int p    = rowbase >> 8;     // panel (256 rows)
    const int r0   = rowbase & 255;    // row offset within panel
#pragma unroll
    for (int j = 0; j < 4; ++j) {
        int kt = j * 4 + wv;
        i32x4 v = *(const i32x4*)&lbuf[rr * KD + kt * BK + kc * 16];
        unsigned char* dp = dst + ((size_t)(p * NKT + kt) * TILE_B)
                                + (size_t)(kc * 256 + r0 + rr) * 16;
        *(i32x4*)dp = v;
    }
}

// ---------------- main GEMM: 256x256 tile, 8 waves, glds staging, conflict-free LDS ----------------
// Stage one 32KB tile: 32 chunks of 1KB; wave wv issues 4 glds (chunks wv*4+i).
__device__ __forceinline__ void stage_tile(unsigned char* lds, const unsigned char* gtile,
                                           int wv, int lane) {
#pragma unroll
    for (int i = 0; i < 4; ++i) {
        int chunk = wv * 4 + i;
        gl_lds16(gtile + chunk * 1024 + lane * 16, lds + chunk * 1024);
    }
}

__global__ __launch_bounds__(512, 2)
void w4a8_gemm_pp(const unsigned char* __restrict__ a8,   // packed, tile-contiguous
                  const unsigned char* __restrict__ w8,
                  const float* __restrict__ per_tok,      // [M]
                  const float* __restrict__ per_chan,     // [E, N]
                  const float* __restrict__ wgs,          // [E, N, NG]
                  float* __restrict__ out)                // [M, N] fp32
{
    __shared__ __align__(16) unsigned char As[2][TILE_B];
    __shared__ __align__(16) unsigned char Bs[2][TILE_B];
    __shared__ float scs[NG][BN];

    // 256 blocks: XCD-chunked -> expert e on XCD e; 32 blocks per expert per XCD
    int bid = blockIdx.x;
    int b2  = (bid & 7) * 32 + (bid >> 3);
    const int e  = b2 >> 5;        // 0..7
    const int tm = (b2 >> 3) & 3;  // 0..3 (256-row panels)
    const int tn = b2 & 7;         // 0..7 (256-col panels)

    const int tid  = threadIdx.x;
    const int lane = tid & 63;
    const int wv   = tid >> 6;   // 0..7
    const int wm   = wv >> 2;    // 0..1  (row half: 128 rows)
    const int wn   = wv & 3;     // 0..3  (col quarter: 64 cols)
    const int lcol = lane & 31;
    const int lhi  = lane >> 5;

    const unsigned char* Ag = a8 + (size_t)((e * 4 + tm) * NKT) * TILE_B;
    const unsigned char* Wg = w8 + (size_t)((e * 8 + tn) * NKT) * TILE_B;

    f32x16 facc[4][2] = {};
    const i32x16 z16 = {};

    // prologue: stage tile 0 + all group scales
    stage_tile(As[0], Ag, wv, lane);
    stage_tile(Bs[0], Wg, wv, lane);
#pragma unroll
    for (int i = 0; i < 8; ++i) {
        int idx = tid + i * 512;
        int g = idx >> 8, n = idx & 255;
        scs[g][n] = wgs[((size_t)e * ND + tn * BN + n) * NG + g];
    }
    __syncthreads();

    int c = 0;
    for (int kt = 0; kt < NKT; ++kt) {
        if (kt + 1 < NKT) {
            stage_tile(As[c ^ 1], Ag + (kt + 1) * TILE_B, wv, lane);
            stage_tile(Bs[c ^ 1], Wg + (kt + 1) * TILE_B, wv, lane);
        }
        const unsigned char* Ac = As[c];
        const unsigned char* Bc = Bs[c];

        float sc0 = scs[kt][wn * 64 +  0 + lcol];
        float sc1 = scs[kt][wn * 64 + 32 + lcol];

        // B fragments for this wave's 64 columns: [ni][ks], lane-consecutive 16B reads
        i32x4 bfr[2][4];
#pragma unroll
        for (int ni = 0; ni < 2; ++ni)
#pragma unroll
            for (int ks = 0; ks < 4; ++ks) {
                int kch = ks * 2 + lhi;
                bfr[ni][ks] = *(const i32x4*)&Bc[kch * (256 * 16) + (wn * 64 + ni * 32 + lcol) * 16];
            }

#pragma unroll
        for (int mi = 0; mi < 4; ++mi) {
            i32x4 afr[4];
#pragma unroll
            for (int ks = 0; ks < 4; ++ks) {
                int kch = ks * 2 + lhi;
                afr[ks] = *(const i32x4*)&Ac[kch * (256 * 16) + (wm * 128 + mi * 32 + lcol) * 16];
            }
            i32x16 acc0, acc1;
            acc0 = __builtin_amdgcn_mfma_i32_32x32x32_i8(afr[0], bfr[0][0], z16, 0, 0, 0);
            acc1 = __builtin_amdgcn_mfma_i32_32x32x32_i8(afr[0], bfr[1][0], z16, 0, 0, 0);
            acc0 = __builtin_amdgcn_mfma_i32_32x32x32_i8(afr[1], bfr[0][1], acc0, 0, 0, 0);
            acc1 = __builtin_amdgcn_mfma_i32_32x32x32_i8(afr[1], bfr[1][1], acc1, 0, 0, 0);
            acc0 = __builtin_amdgcn_mfma_i32_32x32x32_i8(afr[2], bfr[0][2], acc0, 0, 0, 0);
            acc1 = __builtin_amdgcn_mfma_i32_32x32x32_i8(afr[2], bfr[1][2], acc1, 0, 0, 0);
            acc0 = __builtin_amdgcn_mfma_i32_32x32x32_i8(afr[3], bfr[0][3], acc0, 0, 0, 0);
            acc1 = __builtin_amdgcn_mfma_i32_32x32x32_i8(afr[3], bfr[1][3], acc1, 0, 0, 0);
#pragma unroll
            for (int i = 0; i < 16; ++i) {
                facc[mi][0][i] += (float)acc0[i] * sc0;
                facc[mi][1][i] += (float)acc1[i] * sc1;
            }
        }
        __syncthreads();
        c ^= 1;
    }

    // epilogue: per-token and per-channel scales, store fp32
    const float* ptok  = per_tok  + e * MEt + tm * BM;
    const float* pchan = per_chan + (size_t)e * ND + tn * BN;
    float* og = out + (size_t)(e * MEt + tm * BM) * ND + tn * BN;

#pragma unroll
    for (int mi = 0; mi < 4; ++mi) {
        int mb = wm * 128 + mi * 32;
#pragma unroll
        for (int ni = 0; ni < 2; ++ni) {
            int nn = wn * 64 + ni * 32 + lcol;
            float pc = pchan[nn];
#pragma unroll
            for (int rg = 0; rg < 16; ++rg) {
                int mr = mb + (rg & 3) + 8 * (rg >> 2) + 4 * lhi;
                float pt = ptok[mr];
                og[(size_t)mr * ND + nn] = facc[mi][ni][rg] * pt * pc;
            }
        }
    }
}

extern "C" void kernel_launch(void* const* d_in, const int* in_sizes, int n_in,
                              void* d_out, int out_size, void* d_ws, size_t ws_size,
                              hipStream_t stream) {
    const int*   a_q = (const int*)d_in[0];
    const int*   w_q = (const int*)d_in[1];
    const float* pt  = (const float*)d_in[2];
    const float* pc  = (const float*)d_in[3];
    const float* wg  = (const float*)d_in[4];
    float* out = (float*)d_out;

    unsigned char* a8 = (unsigned char*)d_ws;
    unsigned char* w8 = a8 + A_BYTES;

    // (8192 + 16384) rows / 8 rows-per-block = 3072 blocks
    w4a8_prepack<<<dim3((A_ROWS + W_ROWS) / PP_ROWS), dim3(256), 0, stream>>>(a_q, w_q, a8, w8);
    // 8 experts * 4 m-tiles * 8 n-tiles = 256 blocks, 512 threads (8 waves)
    w4a8_gemm_pp<<<dim3(256), dim3(512), 0, stream>>>(a8, w8, pt, pc, wg, out);
}